// Round 7
// baseline (352.523 us; speedup 1.0000x reference)
//
#include <hip/hip_runtime.h>
#include <math.h>

#define NXI 320
#define NCI 8
#define NTI 8
#define MI  65536
#define GI  640
#define G2I (GI*GI)
#define NPIX (NXI*NXI)
#define REC_F 20          // floats per record: {du,1-du,dv,1-dv, 8x(re,im)}
#define NBINS (NTI*G2I)   // 3,276,800 cells over all frames
#define SCAN_BLKS2 (NBINS/4096)   // 800 (4096 bins per block)

typedef float v2f __attribute__((ext_vector_type(2)));

__device__ inline v2f cmul(v2f a, v2f b) {
    v2f axx = __builtin_shufflevector(a, a, 0, 0);
    v2f ayy = __builtin_shufflevector(a, a, 1, 1);
    v2f byx = __builtin_shufflevector(b, b, 1, 0);
    v2f r = axx * b;
    v2f t = ayy * byx;
    return r + v2f{-t.x, t.y};
}

// lane permutation for butterfly stage H: DPP where the pattern fits a
// 16-row permutation (zero DS traffic), ds_swizzle otherwise.
template<int H>
__device__ inline float sxf(float x) {
    if constexpr (H == 1) {        // quad_perm [1,0,3,2]
        return __int_as_float(__builtin_amdgcn_update_dpp(
            __float_as_int(x), __float_as_int(x), 0xB1, 0xF, 0xF, false));
    } else if constexpr (H == 2) { // quad_perm [2,3,0,1]
        return __int_as_float(__builtin_amdgcn_update_dpp(
            __float_as_int(x), __float_as_int(x), 0x4E, 0xF, 0xF, false));
    } else if constexpr (H == 8) { // row_ror:8 == xor-8 within 16-row
        return __int_as_float(__builtin_amdgcn_update_dpp(
            __float_as_int(x), __float_as_int(x), 0x128, 0xF, 0xF, false));
    } else {
        return __shfl_xor(x, H, 64);
    }
}
template<int H>
__device__ inline v2f sxv(v2f v) { return v2f{sxf<H>(v.x), sxf<H>(v.y)}; }

__device__ inline void cell_of(const float* __restrict__ traj, int m, int f,
                               int& i0s, int& j0s, float& du, float& dv)
{
    float tu = traj[(m*2 + 0)*NTI + f];
    float tv = traj[(m*2 + 1)*NTI + f];
    float u = (tu + 0.5f) * (float)GI;
    float v = (tv + 0.5f) * (float)GI;
    float fu = floorf(u), fv = floorf(v);
    du = u - fu; dv = v - fv;
    i0s = (int)fu + GI/2; if (i0s >= GI) i0s -= GI;   // ifftshift folded in
    j0s = (int)fv + GI/2; if (j0s >= GI) j0s -= GI;
}

// ---------------- cell-level counting sort, all frames ----------------
__global__ __launch_bounds__(256) void count_cells(
    const float* __restrict__ traj, int* __restrict__ counts)
{
    int tid = blockIdx.x * 256 + threadIdx.x;   // f*MI + m
    int f = tid >> 16, m = tid & (MI - 1);
    int i0s, j0s; float du, dv;
    cell_of(traj, m, f, i0s, j0s, du, dv);
    atomicAdd(&counts[f*G2I + i0s*GI + j0s], 1);
}

__device__ inline int wave_incl_scan(int v, int lane) {
    #pragma unroll
    for (int d = 1; d < 64; d <<= 1) {
        int y = __shfl_up(v, d, 64);
        if (lane >= d) v += y;
    }
    return v;
}

// 4096 bins per block, barrier-light: wave shuffle scan + 16-entry cross-wave
__global__ __launch_bounds__(1024) void scanA(const int4* __restrict__ counts4,
                                              int4* __restrict__ binstart4,
                                              int* __restrict__ sums)
{
    __shared__ int wtot[16];
    int tid = threadIdx.x, lane = tid & 63, wv = tid >> 6;
    int i = blockIdx.x * 1024 + tid;
    int4 c = counts4[i];
    int s = c.x + c.y + c.z + c.w;
    int incl = wave_incl_scan(s, lane);
    if (lane == 63) wtot[wv] = incl;
    __syncthreads();
    if (wv == 0 && lane < 16) {
        int t = wtot[lane];
        #pragma unroll
        for (int d = 1; d < 16; d <<= 1) {
            int y = __shfl_up(t, d, 64);
            if (lane >= d) t += y;
        }
        wtot[lane] = t;     // inclusive over waves
    }
    __syncthreads();
    int woff = wv ? wtot[wv - 1] : 0;
    int excl = woff + incl - s;
    int4 b;
    b.x = excl; b.y = excl + c.x; b.z = b.y + c.y; b.w = b.z + c.z;
    binstart4[i] = b;
    if (tid == 1023) sums[blockIdx.x] = woff + incl;   // block total
}

// one block: exclusive scan of the 800 chunk sums + sentinels
__global__ __launch_bounds__(1024) void scanB(int* __restrict__ sums,
                                              int* __restrict__ binstart)
{
    __shared__ int tmp[1024];
    int tid = threadIdx.x;
    int v = (tid < SCAN_BLKS2) ? sums[tid] : 0;
    tmp[tid] = v; __syncthreads();
    for (int d = 1; d < 1024; d <<= 1) {
        int y = (tid >= d) ? tmp[tid - d] : 0;
        __syncthreads();
        tmp[tid] += y;
        __syncthreads();
    }
    int incl = tmp[tid];
    if (tid < SCAN_BLKS2) sums[tid] = incl - v;
    if (tid == SCAN_BLKS2 - 1) {
        sums[SCAN_BLKS2] = incl;        // == grand total: sentinel chunk
        binstart[NBINS] = 0;            // so GS(NBINS) == total
    }
}

// slot via atomicSub on counts — no cursor array
__global__ __launch_bounds__(256) void scatter_cells(
    const float* __restrict__ kr, const float* __restrict__ ki,
    const float* __restrict__ traj, const float* __restrict__ dcf,
    int* __restrict__ counts, const int* __restrict__ binstart,
    const int* __restrict__ sums, float* __restrict__ recs)
{
    int tid = blockIdx.x * 256 + threadIdx.x;   // f*MI + m
    int f = tid >> 16, m = tid & (MI - 1);
    int i0s, j0s; float du, dv;
    cell_of(traj, m, f, i0s, j0s, du, dv);
    float w = dcf[m*NTI + f];
    int bin = f*G2I + i0s*GI + j0s;
    int within = atomicSub(&counts[bin], 1) - 1;
    int slot = binstart[bin] + sums[bin >> 12] + within;
    float4* r = (float4*)(recs + (size_t)slot * REC_F);
    r[0] = make_float4(du, 1.f - du, dv, 1.f - dv);   // premultiplied selects
    #pragma unroll
    for (int q = 0; q < 4; ++q) {
        int c0 = 2*q;
        r[1+q] = make_float4(kr[c0*MI + m]*w,     ki[c0*MI + m]*w,
                             kr[(c0+1)*MI + m]*w, ki[(c0+1)*MI + m]*w);
    }
}

// ---------------- register-resident 640-pt iFFT (sign +), packed ----------------
__device__ inline void dft5p(v2f x0, v2f x1, v2f x2, v2f x3, v2f x4, v2f* X)
{
    const float c1 = 0.309016994f, c2 = -0.809016994f;
    const float s1 = 0.951056516f, s2 =  0.587785252f;
    v2f S1 = x1 + x4, D1 = x1 - x4;
    v2f S2 = x2 + x3, D2 = x2 - x3;
    X[0] = x0 + S1 + S2;
    v2f A = x0 + c1*S1 + c2*S2;
    v2f T = s1*D1 + s2*D2;
    v2f B = x0 + c2*S1 + c1*S2;
    v2f U = s2*D1 - s1*D2;
    v2f iT = v2f{-T.y, T.x};
    v2f iU = v2f{-U.y, U.x};
    X[1] = A + iT;  X[4] = A - iT;
    X[2] = B + iU;  X[3] = B - iU;
}

// one DIF butterfly stage (compile-time H), r5-verified sign convention
template<int H, int S>
__device__ inline void bf_stage(v2f* a, int lane)
{
    const float PI = 3.14159265358979f;
    bool low = (lane & H) == 0;
    int kp = (lane << S) & 31;
    float sn, cs;
    __sincosf((2.0f * PI / 64.0f) * (float)kp, &sn, &cs);
    v2f w = low ? v2f{1.f, 0.f} : v2f{cs, sn};
    float sg = low ? 1.f : -1.f;
    v2f sgv = v2f{sg, sg};
    #pragma unroll
    for (int n = 0; n < 10; ++n) {
        v2f p = sxv<H>(a[n]);
        v2f t = sgv * a[n] + p;        // low: p+a ; high: p-a
        a[n] = cmul(t, w);
    }
}

__device__ inline void fft640_pruned(v2f* a, int lane, v2f* line, int xorm)
{
    const float PI = 3.14159265358979f;
    bf_stage<32, 0>(a, lane);
    bf_stage<16, 1>(a, lane);
    bf_stage< 8, 2>(a, lane);
    bf_stage< 4, 3>(a, lane);
    bf_stage< 2, 4>(a, lane);
    bf_stage< 1, 5>(a, lane);
    int k1 = __brev(lane) >> 26;
    float th2 = (2.0f * PI / 640.0f) * (float)k1;
    float sn, cs;
    __sincosf(th2, &sn, &cs);
    v2f wb = v2f{cs, sn};
    v2f w = wb;
    #pragma unroll
    for (int n = 1; n < 10; ++n) {
        a[n] = cmul(a[n], w);
        w = cmul(w, wb);
    }
    v2f E[5], O[5];
    dft5p(a[0], a[2], a[4], a[6], a[8], E);
    dft5p(a[1], a[3], a[5], a[7], a[9], O);
    const v2f tk1 = { 0.809016994f, 0.587785252f};
    const v2f tk2 = { 0.309016994f, 0.951056516f};
    const v2f tk3 = {-0.309016994f, 0.951056516f};
    const v2f tk4 = {-0.809016994f, 0.587785252f};
    v2f t1 = cmul(tk1, O[1]);
    v2f t2 = cmul(tk2, O[2]);
    v2f t3 = cmul(tk3, O[3]);
    v2f t4 = cmul(tk4, O[4]);
    bool hi = (k1 >= 32);
    line[(160 + k1) ^ xorm] = E[0] + O[0];          // k2=0
    line[(224 + k1) ^ xorm] = E[1] + t1;            // k2=1
    int yx = hi ? (k1 - 32) : (288 + k1);           // k2=7 : k2=2
    v2f zx = hi ? (E[2] - t2) : (E[2] + t2);
    line[yx ^ xorm] = zx;
    line[(32 + k1) ^ xorm] = E[3] - t3;             // k2=8
    line[(96 + k1) ^ xorm] = E[4] - t4;             // k2=9
}

// ---- fused atomic-free gather + row FFT: block = (frame, grid-row i) ----
//      Gather = owner-computes with the two row-pass loops MERGED into one
//      loop over concatenated per-lane ranges (verified -8.5us in r5);
//      header carries premultiplied (du,1-du,dv,1-dv) (verified -3us in r6).
__global__ __launch_bounds__(512, 8) void row_fft(
    const int* __restrict__ binstart, const int* __restrict__ sums,
    const float* __restrict__ recs, v2f* __restrict__ rowout)
{
    __shared__ v2f A[NCI][GI];      // 40,960 B exactly -> 4 blocks/CU
    int bid = blockIdx.x;           // f*GI + i
    int i = bid % GI;
    int f = bid / GI;
    int tid = threadIdx.x;
    int im1 = i ? i - 1 : GI - 1;
    const int base0 = f*G2I + i*GI;     // p=0: row i   (1-du)
    const int base1 = f*G2I + im1*GI;   // p=1: row i-1 (du)

    #define GS(b) (binstart[b] + sums[(b) >> 12])

    for (int j = tid; j < GI; j += 512) {
        v2f acc[NCI];
        #pragma unroll
        for (int c = 0; c < NCI; ++c) acc[c] = v2f{0.f, 0.f};
        if (j > 0) {
            int lo0 = GS(base0 + j - 1), mid0 = GS(base0 + j), hi0 = GS(base0 + j + 1);
            int lo1 = GS(base1 + j - 1), mid1 = GS(base1 + j), hi1 = GS(base1 + j + 1);
            int L0 = hi0 - lo0;
            int K  = L0 + (hi1 - lo1);
            for (int k = 0; k < K; ++k) {
                bool p1 = (k >= L0);
                int  s   = p1 ? (lo1 + (k - L0)) : (lo0 + k);
                int  mid = p1 ? mid1 : mid0;
                const float4* R = (const float4*)(recs + (size_t)s*REC_F);
                float4 h4 = R[0];
                float wr = p1 ? h4.x : h4.y;               // du : 1-du
                float w  = wr * ((s < mid) ? h4.z : h4.w); // dv : 1-dv
                float4 d0 = R[1], d1 = R[2], d2 = R[3], d3 = R[4];
                acc[0] += w * v2f{d0.x, d0.y};  acc[1] += w * v2f{d0.z, d0.w};
                acc[2] += w * v2f{d1.x, d1.y};  acc[3] += w * v2f{d1.z, d1.w};
                acc[4] += w * v2f{d2.x, d2.y};  acc[5] += w * v2f{d2.z, d2.w};
                acc[6] += w * v2f{d3.x, d3.y};  acc[7] += w * v2f{d3.z, d3.w};
            }
        } else {
            #pragma unroll
            for (int p = 0; p < 2; ++p) {
                const int base = p ? base1 : base0;
                #pragma unroll
                for (int side = 0; side < 2; ++side) {
                    int b = base + (side ? 0 : (GI - 1));
                    int s0 = GS(b), s1 = GS(b + 1);
                    for (int s = s0; s < s1; ++s) {
                        const float4* R = (const float4*)(recs + (size_t)s*REC_F);
                        float4 h4 = R[0];
                        float wr = p ? h4.x : h4.y;           // du : 1-du
                        float w  = wr * (side ? h4.w : h4.z); // bin0:1-dv / binG-1:dv
                        float4 d0 = R[1], d1 = R[2], d2 = R[3], d3 = R[4];
                        acc[0] += w * v2f{d0.x, d0.y};  acc[1] += w * v2f{d0.z, d0.w};
                        acc[2] += w * v2f{d1.x, d1.y};  acc[3] += w * v2f{d1.z, d1.w};
                        acc[4] += w * v2f{d2.x, d2.y};  acc[5] += w * v2f{d2.z, d2.w};
                        acc[6] += w * v2f{d3.x, d3.y};  acc[7] += w * v2f{d3.z, d3.w};
                    }
                }
            }
        }
        #pragma unroll
        for (int c = 0; c < NCI; ++c) A[c][j] = acc[c];
    }
    #undef GS
    __syncthreads();

    int wv = tid >> 6, lane = tid & 63;
    v2f a[10];
    #pragma unroll
    for (int n = 0; n < 10; ++n) a[n] = A[wv][10*lane + n];
    fft640_pruned(a, lane, A[wv], 0);
    v2f* dst = rowout + (((size_t)f*NCI + wv)*GI + i)*NXI;
    #pragma unroll
    for (int q = 0; q < 5; ++q) {
        int yc = lane + 64*q;
        dst[yc] = A[wv][yc];
    }
}

// ---- col FFT + crop + combine: block = (frame, coil-half, y-group of 8) ----
//      = round-0 col_fft (identical staging/swizzle/FFT/occupancy) with a
//      4-coil loop and the colimg write replaced by a conj(csm)*g register
//      accumulate (acc[5] = +10 VGPR; NO prefetch, NO csm preload — the
//      r3 spill sources). Deapod deferred to warp_sum. 2 half-partials.
__global__ __launch_bounds__(512, 8) void col_fft_combine(
    const v2f* __restrict__ rowout, const float* __restrict__ csr,
    const float* __restrict__ csi, float2* __restrict__ img2)
{
    __shared__ v2f A[8][GI];        // 40,960 B -> 4 blocks/CU
    int bid = blockIdx.x;
    int g = bid % 40;
    int h = (bid / 40) & 1;
    int f = bid / 80;
    int y0 = g * 8;
    int c0 = h * 4;
    int tid = threadIdx.x;
    int wv = tid >> 6, lane = tid & 63;
    int xm = 4 * (wv & 3);

    v2f acc[5];
    #pragma unroll
    for (int q = 0; q < 5; ++q) acc[q] = v2f{0.f, 0.f};

    for (int cc = 0; cc < 4; ++cc) {
        int c = c0 + cc;
        const v2f* src = rowout + ((size_t)f*NCI + c)*GI*NXI + y0;
        for (int idx = tid; idx < 8*GI; idx += 512) {
            int l = idx & 7, k = idx >> 3;
            A[l][k ^ (4*(l & 3))] = src[(size_t)k*NXI + l];
        }
        __syncthreads();
        v2f a[10];
        #pragma unroll
        for (int n = 0; n < 10; ++n) a[n] = A[wv][(10*lane + n) ^ xm];
        fft640_pruned(a, lane, A[wv], xm);
        __syncthreads();
        const float* cr = csr + (size_t)c*NPIX;
        const float* ci = csi + (size_t)c*NPIX;
        #pragma unroll
        for (int q = 0; q < 5; ++q) {
            int P = tid + 512*q; int x = P >> 3, l = P & 7;
            v2f gv = A[l][x ^ (4*(l & 3))];
            int pix = x*NXI + y0 + l;
            float crv = cr[pix], civ = ci[pix];
            acc[q].x += crv*gv.x + civ*gv.y;
            acc[q].y += crv*gv.y - civ*gv.x;
        }
        __syncthreads();    // done reading A before next coil's stage
    }
    float2* dst = img2 + ((size_t)h*NTI + f) * NPIX;
    #pragma unroll
    for (int q = 0; q < 5; ++q) {
        int P = tid + 512*q; int x = P >> 3, l = P & 7;
        dst[(size_t)x*NXI + y0 + l] = make_float2(acc[q].x, acc[q].y);
    }
}

// ------- warp all frames + sum: deapod via block-local LDS table, -------
//         sums the 2 coil-half partials (r3-verified math)
__global__ __launch_bounds__(256) void warp_sum(
    const float2* __restrict__ img2, const float* __restrict__ motions,
    float* __restrict__ out)
{
    __shared__ float sdinv[NXI];
    int tid = threadIdx.x;
    const float PI = 3.14159265358979f;
    for (int idx = tid; idx < NXI; idx += 256) {
        float t = (idx - 160) * (1.0f/GI);
        float d = 1.0f;
        if (idx != 160) { float s = __sinf(PI*t) / (PI*t); d = s*s; }
        sdinv[idx] = (1.0f/GI) / d;
    }
    __syncthreads();
    int pix = blockIdx.x * 256 + tid;
    int x = pix / NXI, y = pix - x*NXI;
    float accr = 0.f, acci = 0.f;
    #pragma unroll
    for (int f = 0; f < NTI; ++f) {
        float fx = motions[(size_t)(pix*2 + 0)*NTI + f];
        float fy = motions[(size_t)(pix*2 + 1)*NTI + f];
        float xs = fminf(fmaxf((float)x + fx, 0.0f), (float)(NXI-1));
        float ys = fminf(fmaxf((float)y + fy, 0.0f), (float)(NXI-1));
        int x0 = (int)floorf(xs);
        int y0 = (int)floorf(ys);
        int x1 = min(x0+1, NXI-1);
        int y1 = min(y0+1, NXI-1);
        float dx = xs - (float)x0;
        float dy = ys - (float)y0;
        float ax0 = sdinv[x0], ax1 = sdinv[x1];
        float ay0 = sdinv[y0], ay1 = sdinv[y1];
        float w00 = (1.f-dx)*(1.f-dy)*ax0*ay0, w10 = dx*(1.f-dy)*ax1*ay0;
        float w01 = (1.f-dx)*dy*ax0*ay1,       w11 = dx*dy*ax1*ay1;
        #pragma unroll
        for (int h = 0; h < 2; ++h) {
            const float2* im = img2 + ((size_t)h*NTI + f)*NPIX;
            float2 v00 = im[x0*NXI + y0];
            float2 v10 = im[x1*NXI + y0];
            float2 v01 = im[x0*NXI + y1];
            float2 v11 = im[x1*NXI + y1];
            accr += w00*v00.x + w10*v10.x + w01*v01.x + w11*v11.x;
            acci += w00*v00.y + w10*v10.y + w01*v01.y + w11*v11.y;
        }
    }
    out[pix*2+0] = accr;
    out[pix*2+1] = acci;
}

extern "C" void kernel_launch(void* const* d_in, const int* in_sizes, int n_in,
                              void* d_out, int out_size, void* d_ws, size_t ws_size,
                              hipStream_t stream)
{
    const float* kr   = (const float*)d_in[0];
    const float* ki   = (const float*)d_in[1];
    const float* traj = (const float*)d_in[2];
    const float* csr  = (const float*)d_in[3];
    const float* csi  = (const float*)d_in[4];
    const float* dcf  = (const float*)d_in[5];
    const float* mot  = (const float*)d_in[6];
    float* out = (float*)d_out;

    char* ws = (char*)d_ws;
    float*  recs     = (float*)ws;                       // 41.94 MB
    ws += (size_t)NTI * MI * REC_F * sizeof(float);
    v2f*    rowout   = (v2f*)ws;                         // 104.86 MB
    ws += (size_t)NTI * NCI * GI * NXI * sizeof(float2);
    float2* img2     = (float2*)ws;                      // 13.1 MB (2 halves)
    ws += (size_t)2 * NTI * NPIX * sizeof(float2);
    int*    counts   = (int*)ws;  ws += (size_t)NBINS * sizeof(int);        // 13.1 MB
    int*    binstart = (int*)ws;  ws += ((size_t)NBINS + 16) * sizeof(int); // 13.1 MB
    int*    sums     = (int*)ws;  ws += 16384;

    hipMemsetAsync(counts, 0, (size_t)NBINS * sizeof(int), stream);
    count_cells  <<<NTI*MI/256, 256, 0, stream>>>(traj, counts);
    scanA        <<<SCAN_BLKS2, 1024, 0, stream>>>((const int4*)counts,
                                                   (int4*)binstart, sums);
    scanB        <<<1,          1024, 0, stream>>>(sums, binstart);
    scatter_cells<<<NTI*MI/256, 256, 0, stream>>>(kr, ki, traj, dcf, counts,
                                                  binstart, sums, recs);
    row_fft      <<<NTI*GI,     512, 0, stream>>>(binstart, sums, recs, rowout);
    col_fft_combine<<<NTI*2*40, 512, 0, stream>>>(rowout, csr, csi, img2);
    warp_sum     <<<NPIX/256,   256, 0, stream>>>(img2, mot, out);
}

// Round 8
// 280.006 us; speedup vs baseline: 1.2590x; 1.2590x over previous
//
#include <hip/hip_runtime.h>
#include <math.h>

#define NXI 320
#define NCI 8
#define NTI 8
#define MI  65536
#define GI  640
#define G2I (GI*GI)
#define NPIX (NXI*NXI)
#define REC_F 20          // floats per record: {du,1-du,dv,1-dv, 8x(re,im)}
#define NBINS (NTI*G2I)   // 3,276,800 cells over all frames
#define SCAN_BLKS2 (NBINS/4096)   // 800 (4096 bins per block)

typedef float v2f __attribute__((ext_vector_type(2)));

__device__ inline v2f cmul(v2f a, v2f b) {
    v2f axx = __builtin_shufflevector(a, a, 0, 0);
    v2f ayy = __builtin_shufflevector(a, a, 1, 1);
    v2f byx = __builtin_shufflevector(b, b, 1, 0);
    v2f r = axx * b;
    v2f t = ayy * byx;
    return r + v2f{-t.x, t.y};
}

// lane permutation for butterfly stage H: DPP where the pattern fits a
// 16-row permutation (zero DS traffic), ds_swizzle otherwise.
template<int H>
__device__ inline float sxf(float x) {
    if constexpr (H == 1) {        // quad_perm [1,0,3,2]
        return __int_as_float(__builtin_amdgcn_update_dpp(
            __float_as_int(x), __float_as_int(x), 0xB1, 0xF, 0xF, false));
    } else if constexpr (H == 2) { // quad_perm [2,3,0,1]
        return __int_as_float(__builtin_amdgcn_update_dpp(
            __float_as_int(x), __float_as_int(x), 0x4E, 0xF, 0xF, false));
    } else if constexpr (H == 8) { // row_ror:8 == xor-8 within 16-row
        return __int_as_float(__builtin_amdgcn_update_dpp(
            __float_as_int(x), __float_as_int(x), 0x128, 0xF, 0xF, false));
    } else {
        return __shfl_xor(x, H, 64);
    }
}
template<int H>
__device__ inline v2f sxv(v2f v) { return v2f{sxf<H>(v.x), sxf<H>(v.y)}; }

__device__ inline void cell_of(const float* __restrict__ traj, int m, int f,
                               int& i0s, int& j0s, float& du, float& dv)
{
    float tu = traj[(m*2 + 0)*NTI + f];
    float tv = traj[(m*2 + 1)*NTI + f];
    float u = (tu + 0.5f) * (float)GI;
    float v = (tv + 0.5f) * (float)GI;
    float fu = floorf(u), fv = floorf(v);
    du = u - fu; dv = v - fv;
    i0s = (int)fu + GI/2; if (i0s >= GI) i0s -= GI;   // ifftshift folded in
    j0s = (int)fv + GI/2; if (j0s >= GI) j0s -= GI;
}

// ---------------- cell-level counting sort, all frames ----------------
__global__ __launch_bounds__(256) void count_cells(
    const float* __restrict__ traj, int* __restrict__ counts)
{
    int tid = blockIdx.x * 256 + threadIdx.x;   // f*MI + m
    int f = tid >> 16, m = tid & (MI - 1);
    int i0s, j0s; float du, dv;
    cell_of(traj, m, f, i0s, j0s, du, dv);
    atomicAdd(&counts[f*G2I + i0s*GI + j0s], 1);
}

__device__ inline int wave_incl_scan(int v, int lane) {
    #pragma unroll
    for (int d = 1; d < 64; d <<= 1) {
        int y = __shfl_up(v, d, 64);
        if (lane >= d) v += y;
    }
    return v;
}

// 4096 bins per block, barrier-light: wave shuffle scan + 16-entry cross-wave
__global__ __launch_bounds__(1024) void scanA(const int4* __restrict__ counts4,
                                              int4* __restrict__ binstart4,
                                              int* __restrict__ sums)
{
    __shared__ int wtot[16];
    int tid = threadIdx.x, lane = tid & 63, wv = tid >> 6;
    int i = blockIdx.x * 1024 + tid;
    int4 c = counts4[i];
    int s = c.x + c.y + c.z + c.w;
    int incl = wave_incl_scan(s, lane);
    if (lane == 63) wtot[wv] = incl;
    __syncthreads();
    if (wv == 0 && lane < 16) {
        int t = wtot[lane];
        #pragma unroll
        for (int d = 1; d < 16; d <<= 1) {
            int y = __shfl_up(t, d, 64);
            if (lane >= d) t += y;
        }
        wtot[lane] = t;     // inclusive over waves
    }
    __syncthreads();
    int woff = wv ? wtot[wv - 1] : 0;
    int excl = woff + incl - s;
    int4 b;
    b.x = excl; b.y = excl + c.x; b.z = b.y + c.y; b.w = b.z + c.z;
    binstart4[i] = b;
    if (tid == 1023) sums[blockIdx.x] = woff + incl;   // block total
}

// one block: exclusive scan of the 800 chunk sums + sentinels
__global__ __launch_bounds__(1024) void scanB(int* __restrict__ sums,
                                              int* __restrict__ binstart)
{
    __shared__ int tmp[1024];
    int tid = threadIdx.x;
    int v = (tid < SCAN_BLKS2) ? sums[tid] : 0;
    tmp[tid] = v; __syncthreads();
    for (int d = 1; d < 1024; d <<= 1) {
        int y = (tid >= d) ? tmp[tid - d] : 0;
        __syncthreads();
        tmp[tid] += y;
        __syncthreads();
    }
    int incl = tmp[tid];
    if (tid < SCAN_BLKS2) sums[tid] = incl - v;
    if (tid == SCAN_BLKS2 - 1) {
        sums[SCAN_BLKS2] = incl;        // == grand total: sentinel chunk
        binstart[NBINS] = 0;            // so GS(NBINS) == total
    }
}

// slot via atomicSub on counts — no cursor array
__global__ __launch_bounds__(256) void scatter_cells(
    const float* __restrict__ kr, const float* __restrict__ ki,
    const float* __restrict__ traj, const float* __restrict__ dcf,
    int* __restrict__ counts, const int* __restrict__ binstart,
    const int* __restrict__ sums, float* __restrict__ recs)
{
    int tid = blockIdx.x * 256 + threadIdx.x;   // f*MI + m
    int f = tid >> 16, m = tid & (MI - 1);
    int i0s, j0s; float du, dv;
    cell_of(traj, m, f, i0s, j0s, du, dv);
    float w = dcf[m*NTI + f];
    int bin = f*G2I + i0s*GI + j0s;
    int within = atomicSub(&counts[bin], 1) - 1;
    int slot = binstart[bin] + sums[bin >> 12] + within;
    float4* r = (float4*)(recs + (size_t)slot * REC_F);
    r[0] = make_float4(du, 1.f - du, dv, 1.f - dv);   // premultiplied selects
    #pragma unroll
    for (int q = 0; q < 4; ++q) {
        int c0 = 2*q;
        r[1+q] = make_float4(kr[c0*MI + m]*w,     ki[c0*MI + m]*w,
                             kr[(c0+1)*MI + m]*w, ki[(c0+1)*MI + m]*w);
    }
}

// ---------------- register-resident 640-pt iFFT (sign +), packed ----------------
__device__ inline void dft5p(v2f x0, v2f x1, v2f x2, v2f x3, v2f x4, v2f* X)
{
    const float c1 = 0.309016994f, c2 = -0.809016994f;
    const float s1 = 0.951056516f, s2 =  0.587785252f;
    v2f S1 = x1 + x4, D1 = x1 - x4;
    v2f S2 = x2 + x3, D2 = x2 - x3;
    X[0] = x0 + S1 + S2;
    v2f A = x0 + c1*S1 + c2*S2;
    v2f T = s1*D1 + s2*D2;
    v2f B = x0 + c2*S1 + c1*S2;
    v2f U = s2*D1 - s1*D2;
    v2f iT = v2f{-T.y, T.x};
    v2f iU = v2f{-U.y, U.x};
    X[1] = A + iT;  X[4] = A - iT;
    X[2] = B + iU;  X[3] = B - iU;
}

// one DIF butterfly stage (compile-time H), r5-verified sign convention
template<int H, int S>
__device__ inline void bf_stage(v2f* a, int lane)
{
    const float PI = 3.14159265358979f;
    bool low = (lane & H) == 0;
    int kp = (lane << S) & 31;
    float sn, cs;
    __sincosf((2.0f * PI / 64.0f) * (float)kp, &sn, &cs);
    v2f w = low ? v2f{1.f, 0.f} : v2f{cs, sn};
    float sg = low ? 1.f : -1.f;
    v2f sgv = v2f{sg, sg};
    #pragma unroll
    for (int n = 0; n < 10; ++n) {
        v2f p = sxv<H>(a[n]);
        v2f t = sgv * a[n] + p;        // low: p+a ; high: p-a
        a[n] = cmul(t, w);
    }
}

__device__ inline void fft640_pruned(v2f* a, int lane, v2f* line, int xorm)
{
    const float PI = 3.14159265358979f;
    bf_stage<32, 0>(a, lane);
    bf_stage<16, 1>(a, lane);
    bf_stage< 8, 2>(a, lane);
    bf_stage< 4, 3>(a, lane);
    bf_stage< 2, 4>(a, lane);
    bf_stage< 1, 5>(a, lane);
    int k1 = __brev(lane) >> 26;
    float th2 = (2.0f * PI / 640.0f) * (float)k1;
    float sn, cs;
    __sincosf(th2, &sn, &cs);
    v2f wb = v2f{cs, sn};
    v2f w = wb;
    #pragma unroll
    for (int n = 1; n < 10; ++n) {
        a[n] = cmul(a[n], w);
        w = cmul(w, wb);
    }
    v2f E[5], O[5];
    dft5p(a[0], a[2], a[4], a[6], a[8], E);
    dft5p(a[1], a[3], a[5], a[7], a[9], O);
    const v2f tk1 = { 0.809016994f, 0.587785252f};
    const v2f tk2 = { 0.309016994f, 0.951056516f};
    const v2f tk3 = {-0.309016994f, 0.951056516f};
    const v2f tk4 = {-0.809016994f, 0.587785252f};
    v2f t1 = cmul(tk1, O[1]);
    v2f t2 = cmul(tk2, O[2]);
    v2f t3 = cmul(tk3, O[3]);
    v2f t4 = cmul(tk4, O[4]);
    bool hi = (k1 >= 32);
    line[(160 + k1) ^ xorm] = E[0] + O[0];          // k2=0
    line[(224 + k1) ^ xorm] = E[1] + t1;            // k2=1
    int yx = hi ? (k1 - 32) : (288 + k1);           // k2=7 : k2=2
    v2f zx = hi ? (E[2] - t2) : (E[2] + t2);
    line[yx ^ xorm] = zx;
    line[(32 + k1) ^ xorm] = E[3] - t3;             // k2=8
    line[(96 + k1) ^ xorm] = E[4] - t4;             // k2=9
}

// ---- fused atomic-free gather + row FFT: block = (frame, grid-row i) ----
//      Gather = merged-cursor owner-computes (r5, -8.5us) + premult header
//      (r6, -3us) + SOFTWARE-PIPELINED record loads: record k+1's 5xfloat4
//      issued while record k's weight+FMA computes (divergent loops are not
//      rotated by the compiler; this hides the ~200cy L2 latency head).
__global__ __launch_bounds__(512, 8) void row_fft(
    const int* __restrict__ binstart, const int* __restrict__ sums,
    const float* __restrict__ recs, v2f* __restrict__ rowout)
{
    __shared__ v2f A[NCI][GI];      // 40,960 B exactly -> 4 blocks/CU
    int bid = blockIdx.x;           // f*GI + i
    int i = bid % GI;
    int f = bid / GI;
    int tid = threadIdx.x;
    int im1 = i ? i - 1 : GI - 1;
    const int base0 = f*G2I + i*GI;     // p=0: row i   (1-du)
    const int base1 = f*G2I + im1*GI;   // p=1: row i-1 (du)

    #define GS(b) (binstart[b] + sums[(b) >> 12])

    for (int j = tid; j < GI; j += 512) {
        v2f acc[NCI];
        #pragma unroll
        for (int c = 0; c < NCI; ++c) acc[c] = v2f{0.f, 0.f};
        if (j > 0) {
            int lo0 = GS(base0 + j - 1), mid0 = GS(base0 + j), hi0 = GS(base0 + j + 1);
            int lo1 = GS(base1 + j - 1), mid1 = GS(base1 + j), hi1 = GS(base1 + j + 1);
            int L0 = hi0 - lo0;
            int K  = L0 + (hi1 - lo1);
            if (K > 0) {
                // prologue: load record 0
                int sC = (0 >= L0) ? lo1 : lo0;
                const float4* Rc = (const float4*)(recs + (size_t)sC*REC_F);
                float4 h  = Rc[0];
                float4 e0 = Rc[1], e1 = Rc[2], e2 = Rc[3], e3 = Rc[4];
                for (int k = 0; k < K; ++k) {
                    // issue next record's loads (clamped at tail)
                    int kn = (k + 1 < K) ? (k + 1) : k;
                    bool p1n = (kn >= L0);
                    int sN = p1n ? (lo1 + (kn - L0)) : (lo0 + kn);
                    const float4* Rn = (const float4*)(recs + (size_t)sN*REC_F);
                    float4 hN = Rn[0];
                    float4 f0 = Rn[1], f1 = Rn[2], f2 = Rn[3], f3 = Rn[4];
                    // consume current record
                    bool p1 = (k >= L0);
                    int  s   = p1 ? (lo1 + (k - L0)) : (lo0 + k);
                    int  mid = p1 ? mid1 : mid0;
                    float wr = p1 ? h.x : h.y;               // du : 1-du
                    float w  = wr * ((s < mid) ? h.z : h.w); // dv : 1-dv
                    acc[0] += w * v2f{e0.x, e0.y};  acc[1] += w * v2f{e0.z, e0.w};
                    acc[2] += w * v2f{e1.x, e1.y};  acc[3] += w * v2f{e1.z, e1.w};
                    acc[4] += w * v2f{e2.x, e2.y};  acc[5] += w * v2f{e2.z, e2.w};
                    acc[6] += w * v2f{e3.x, e3.y};  acc[7] += w * v2f{e3.z, e3.w};
                    h = hN; e0 = f0; e1 = f1; e2 = f2; e3 = f3;
                }
            }
        } else {
            #pragma unroll
            for (int p = 0; p < 2; ++p) {
                const int base = p ? base1 : base0;
                #pragma unroll
                for (int side = 0; side < 2; ++side) {
                    int b = base + (side ? 0 : (GI - 1));
                    int s0 = GS(b), s1 = GS(b + 1);
                    for (int s = s0; s < s1; ++s) {
                        const float4* R = (const float4*)(recs + (size_t)s*REC_F);
                        float4 h4 = R[0];
                        float wr = p ? h4.x : h4.y;           // du : 1-du
                        float w  = wr * (side ? h4.w : h4.z); // bin0:1-dv / binG-1:dv
                        float4 d0 = R[1], d1 = R[2], d2 = R[3], d3 = R[4];
                        acc[0] += w * v2f{d0.x, d0.y};  acc[1] += w * v2f{d0.z, d0.w};
                        acc[2] += w * v2f{d1.x, d1.y};  acc[3] += w * v2f{d1.z, d1.w};
                        acc[4] += w * v2f{d2.x, d2.y};  acc[5] += w * v2f{d2.z, d2.w};
                        acc[6] += w * v2f{d3.x, d3.y};  acc[7] += w * v2f{d3.z, d3.w};
                    }
                }
            }
        }
        #pragma unroll
        for (int c = 0; c < NCI; ++c) A[c][j] = acc[c];
    }
    #undef GS
    __syncthreads();

    int wv = tid >> 6, lane = tid & 63;
    v2f a[10];
    #pragma unroll
    for (int n = 0; n < 10; ++n) a[n] = A[wv][10*lane + n];
    fft640_pruned(a, lane, A[wv], 0);
    v2f* dst = rowout + (((size_t)f*NCI + wv)*GI + i)*NXI;
    #pragma unroll
    for (int q = 0; q < 5; ++q) {
        int yc = lane + 64*q;
        dst[yc] = A[wv][yc];
    }
}

// ---- col FFT + crop: block = (frame, coil, y-group of 8) ----
__global__ __launch_bounds__(512, 8) void col_fft(
    const v2f* __restrict__ rowout, v2f* __restrict__ colimg)
{
    __shared__ v2f A[8][GI];
    int bid = blockIdx.x;
    int g = bid % 40;
    int c = (bid / 40) % NCI;
    int f = bid / (40*NCI);
    int y0 = g * 8;
    int tid = threadIdx.x;
    const v2f* src = rowout + ((size_t)f*NCI + c)*GI*NXI + y0;
    for (int idx = tid; idx < 8*GI; idx += 512) {
        int l = idx & 7, k = idx >> 3;
        A[l][k ^ (4*(l & 3))] = src[(size_t)k*NXI + l];
    }
    __syncthreads();
    int wv = tid >> 6, lane = tid & 63;
    int xm = 4 * (wv & 3);
    v2f a[10];
    #pragma unroll
    for (int n = 0; n < 10; ++n) a[n] = A[wv][(10*lane + n) ^ xm];
    fft640_pruned(a, lane, A[wv], xm);
    __syncthreads();
    v2f* dst = colimg + ((size_t)f*NCI + c)*NPIX + y0;
    for (int idx = tid; idx < 8*NXI; idx += 512) {
        int l = idx & 7, xx = idx >> 3;
        dst[(size_t)xx*NXI + l] = A[l][xx ^ (4*(l & 3))];
    }
}

// ------------- deapodize + coil combine -------------
__global__ __launch_bounds__(256) void combine_kernel(
    const float2* __restrict__ colimg, const float* __restrict__ csr,
    const float* __restrict__ csi, float2* __restrict__ img)
{
    int f = blockIdx.y;
    int pix = blockIdx.x * 256 + threadIdx.x;
    int x = pix / NXI, y = pix - x*NXI;
    const float PI = 3.14159265358979f;
    float tx = (x - 160) * (1.0f/GI);
    float ty = (y - 160) * (1.0f/GI);
    float dx = 1.0f, dy = 1.0f;
    if (x != 160) { float s = __sinf(PI*tx) / (PI*tx); dx = s*s; }
    if (y != 160) { float s = __sinf(PI*ty) / (PI*ty); dy = s*s; }
    float scale = 1.0f / ((float)G2I * dx * dy);
    float accr = 0.f, acci = 0.f;
    #pragma unroll
    for (int c = 0; c < NCI; ++c) {
        float2 g = colimg[((size_t)f*NCI + c)*NPIX + pix];
        float cr = csr[c*NPIX + pix];
        float ci = csi[c*NPIX + pix];
        accr += cr*g.x + ci*g.y;
        acci += cr*g.y - ci*g.x;
    }
    img[(size_t)f*NPIX + pix] = make_float2(accr*scale, acci*scale);
}

// ---------------- warp all frames + sum ----------------
__global__ __launch_bounds__(256) void warp_sum(
    const float2* __restrict__ img, const float* __restrict__ motions,
    float* __restrict__ out)
{
    int pix = blockIdx.x * 256 + threadIdx.x;
    int x = pix / NXI, y = pix - x*NXI;
    float accr = 0.f, acci = 0.f;
    #pragma unroll
    for (int f = 0; f < NTI; ++f) {
        float fx = motions[(size_t)(pix*2 + 0)*NTI + f];
        float fy = motions[(size_t)(pix*2 + 1)*NTI + f];
        float xs = fminf(fmaxf((float)x + fx, 0.0f), (float)(NXI-1));
        float ys = fminf(fmaxf((float)y + fy, 0.0f), (float)(NXI-1));
        int x0 = (int)floorf(xs);
        int y0 = (int)floorf(ys);
        int x1 = min(x0+1, NXI-1);
        int y1 = min(y0+1, NXI-1);
        float dx = xs - (float)x0;
        float dy = ys - (float)y0;
        const float2* im = img + (size_t)f*NPIX;
        float2 v00 = im[x0*NXI + y0];
        float2 v10 = im[x1*NXI + y0];
        float2 v01 = im[x0*NXI + y1];
        float2 v11 = im[x1*NXI + y1];
        float w00 = (1.f-dx)*(1.f-dy), w10 = dx*(1.f-dy);
        float w01 = (1.f-dx)*dy,       w11 = dx*dy;
        accr += w00*v00.x + w10*v10.x + w01*v01.x + w11*v11.x;
        acci += w00*v00.y + w10*v10.y + w01*v01.y + w11*v11.y;
    }
    out[pix*2+0] = accr;
    out[pix*2+1] = acci;
}

extern "C" void kernel_launch(void* const* d_in, const int* in_sizes, int n_in,
                              void* d_out, int out_size, void* d_ws, size_t ws_size,
                              hipStream_t stream)
{
    const float* kr   = (const float*)d_in[0];
    const float* ki   = (const float*)d_in[1];
    const float* traj = (const float*)d_in[2];
    const float* csr  = (const float*)d_in[3];
    const float* csi  = (const float*)d_in[4];
    const float* dcf  = (const float*)d_in[5];
    const float* mot  = (const float*)d_in[6];
    float* out = (float*)d_out;

    char* ws = (char*)d_ws;
    float*  recs     = (float*)ws;                       // 41.94 MB
    ws += (size_t)NTI * MI * REC_F * sizeof(float);
    v2f*    rowout   = (v2f*)ws;                         // 104.86 MB
    ws += (size_t)NTI * NCI * GI * NXI * sizeof(float2);
    float2* colimg   = (float2*)ws;                      // 52.43 MB
    ws += (size_t)NTI * NCI * NPIX * sizeof(float2);
    float2* img      = (float2*)ws;                      // 6.55 MB
    ws += (size_t)NTI * NPIX * sizeof(float2);
    int*    counts   = (int*)ws;  ws += (size_t)NBINS * sizeof(int);        // 13.1 MB
    int*    binstart = (int*)ws;  ws += ((size_t)NBINS + 16) * sizeof(int); // 13.1 MB
    int*    sums     = (int*)ws;  ws += 16384;

    hipMemsetAsync(counts, 0, (size_t)NBINS * sizeof(int), stream);
    count_cells  <<<NTI*MI/256, 256, 0, stream>>>(traj, counts);
    scanA        <<<SCAN_BLKS2, 1024, 0, stream>>>((const int4*)counts,
                                                   (int4*)binstart, sums);
    scanB        <<<1,          1024, 0, stream>>>(sums, binstart);
    scatter_cells<<<NTI*MI/256, 256, 0, stream>>>(kr, ki, traj, dcf, counts,
                                                  binstart, sums, recs);
    row_fft      <<<NTI*GI,     512, 0, stream>>>(binstart, sums, recs, rowout);
    col_fft      <<<NTI*NCI*40, 512, 0, stream>>>(rowout, (v2f*)colimg);
    combine_kernel<<<dim3(NPIX/256, NTI), 256, 0, stream>>>(colimg, csr, csi, img);
    warp_sum     <<<NPIX/256,   256, 0, stream>>>(img, mot, out);
}